// Round 5
// baseline (717.141 us; speedup 1.0000x reference)
//
#include <hip/hip_runtime.h>

typedef unsigned short u16;
typedef unsigned int   u32;
typedef __attribute__((ext_vector_type(8))) short bf16x8;   // 8 bf16 (4 VGPRs)
typedef __attribute__((ext_vector_type(4))) float f32x4;    // mfma acc

#define EPS 1e-5f
#define MFMA(a,b,c) __builtin_amdgcn_mfma_f32_16x16x32_bf16(a,b,c,0,0,0)

__device__ __forceinline__ float bf2f(u32 u) { return __uint_as_float(u << 16); }
__device__ __forceinline__ u16 f2bf(float f) {
  u32 b = __float_as_uint(f);
  return (u16)((b + 0x7fffu + ((b >> 16) & 1u)) >> 16);  // RNE
}
__device__ __forceinline__ u32 fkey(float f) {  // monotone float->u32 (finite)
  u32 b = __float_as_uint(f);
  return (b & 0x80000000u) ? ~b : (b | 0x80000000u);
}

// B-frag swizzle: idx -> f=idx>>9, L=(idx>>3)&63, j=idx&7
// element = W[(f>>2)*32 + ((L>>4)<<3) + j][((f&3)<<4) + (L&15)]
__device__ __forceinline__ void swizzleW(const float* __restrict__ W, u16* __restrict__ s,
                                         int nelem, int tid, int nthr) {
  for (int idx = tid; idx < nelem; idx += nthr) {
    int f = idx >> 9, L = (idx >> 3) & 63, j = idx & 7;
    int k = (f >> 2) * 32 + ((L >> 4) << 3) + j, n = ((f & 3) << 4) + (L & 15);
    s[idx] = f2bf(W[k * 64 + n]);
  }
}

// ---- stage A (MFMA): h = relu(relu(LN(X@W1+b1)) @ W2 + b2) -> bf16 ; + dst histogram ----
__launch_bounds__(256, 3)
__global__ void k_h(const float* __restrict__ X,
                    const float* __restrict__ W1, const float* __restrict__ b1,
                    const float* __restrict__ g1, const float* __restrict__ be1,
                    const float* __restrict__ W2, const float* __restrict__ b2,
                    const float* __restrict__ te, u32* __restrict__ counts,
                    u16* __restrict__ hb, int N, int E) {
  __shared__ __align__(16) u16 sW1[32 * 512];
  __shared__ __align__(16) u16 sW2[8 * 512];
  __shared__ __align__(16) u16 st[4][16 * 72];

  swizzleW(W1, sW1, 16384, threadIdx.x, 256);
  swizzleW(W2, sW2, 4096, threadIdx.x, 256);
  __syncthreads();

  int lane = threadIdx.x & 63, wave = threadIdx.x >> 6;
  int m = lane & 15, quad = lane >> 4, koff = quad * 8, col0 = m;

  float b1v[4], g1v[4], be1v[4], b2v[4];
  #pragma unroll
  for (int nt = 0; nt < 4; nt++) {
    int c = nt * 16 + col0;
    b1v[nt] = b1[c]; g1v[nt] = g1[c]; be1v[nt] = be1[c]; b2v[nt] = b2[c];
  }

  int ntiles = (N + 15) / 16;
  int wid = blockIdx.x * 4 + wave, nw = gridDim.x * 4;
  for (int tile = wid; tile < ntiles; tile += nw) {
    int n0 = tile * 16;
    int nm = min(n0 + m, N - 1);
    const float* xr = X + (size_t)nm * 256 + koff;

    f32x4 acc[4] = {};
    #pragma unroll 4
    for (int ks = 0; ks < 8; ks++) {
      float4 u0 = *(const float4*)(xr + ks * 32);
      float4 u1 = *(const float4*)(xr + ks * 32 + 4);
      bf16x8 a;
      a[0] = (short)f2bf(u0.x); a[1] = (short)f2bf(u0.y);
      a[2] = (short)f2bf(u0.z); a[3] = (short)f2bf(u0.w);
      a[4] = (short)f2bf(u1.x); a[5] = (short)f2bf(u1.y);
      a[6] = (short)f2bf(u1.z); a[7] = (short)f2bf(u1.w);
      #pragma unroll
      for (int nt = 0; nt < 4; nt++) {
        bf16x8 b = *(const bf16x8*)(sW1 + (ks * 4 + nt) * 512 + lane * 8);
        acc[nt] = MFMA(a, b, acc[nt]);
      }
    }

    float v[4][4];
    #pragma unroll
    for (int nt = 0; nt < 4; nt++)
      #pragma unroll
      for (int r = 0; r < 4; r++) v[nt][r] = acc[nt][r] + b1v[nt];

    #pragma unroll
    for (int r = 0; r < 4; r++) {
      float s = v[0][r] + v[1][r] + v[2][r] + v[3][r];
      #pragma unroll
      for (int mk = 8; mk >= 1; mk >>= 1) s += __shfl_xor(s, mk, 64);
      float mu = s * (1.f / 64.f);
      float q = 0.f;
      #pragma unroll
      for (int nt = 0; nt < 4; nt++) { float d = v[nt][r] - mu; q += d * d; }
      #pragma unroll
      for (int mk = 8; mk >= 1; mk >>= 1) q += __shfl_xor(q, mk, 64);
      float rs = rsqrtf(q * (1.f / 64.f) + EPS);
      #pragma unroll
      for (int nt = 0; nt < 4; nt++) {
        float h1 = fmaxf(fmaf((v[nt][r] - mu) * rs, g1v[nt], be1v[nt]), 0.f);
        st[wave][(quad * 4 + r) * 72 + nt * 16 + col0] = f2bf(h1);
      }
    }
    __builtin_amdgcn_wave_barrier();

    f32x4 acc2[4] = {};
    #pragma unroll
    for (int ks = 0; ks < 2; ks++) {
      bf16x8 a2 = *(const bf16x8*)(st[wave] + m * 72 + ks * 32 + koff);
      #pragma unroll
      for (int nt = 0; nt < 4; nt++) {
        bf16x8 b = *(const bf16x8*)(sW2 + (ks * 4 + nt) * 512 + lane * 8);
        acc2[nt] = MFMA(a2, b, acc2[nt]);
      }
    }
    __builtin_amdgcn_wave_barrier();

    #pragma unroll
    for (int nt = 0; nt < 4; nt++)
      #pragma unroll
      for (int r = 0; r < 4; r++) {
        int row = n0 + quad * 4 + r;
        if (row < N)
          hb[(size_t)row * 64 + nt * 16 + col0] = f2bf(fmaxf(acc2[nt][r] + b2v[nt], 0.f));
      }
  }

  // phase 2: dst histogram (grid-stride)
  int tid = blockIdx.x * 256 + threadIdx.x;
  int nth = gridDim.x * 256;
  for (int e = tid; e < E; e += nth) {
    float dv = te[(size_t)e * 4 + 1];
    int d = min(max((int)dv, 0), N - 1);
    atomicAdd(&counts[d], 1u);
  }
}

// ---- fused exclusive scan (single block, 1024 threads): counts -> cursor ----
__launch_bounds__(1024)
__global__ void k_scan(const u32* __restrict__ counts, u32* __restrict__ cursor, int M) {
  __shared__ u32 sh[1024];
  int tid = threadIdx.x;
  int per = (M + 1023) >> 10;
  int lo = tid * per, hi = min(lo + per, M);
  u32 s = 0;
  for (int i = lo; i < hi; i++) s += counts[i];
  sh[tid] = s;
  __syncthreads();
  for (int off = 1; off < 1024; off <<= 1) {
    u32 v = (tid >= off) ? sh[tid - off] : 0u;
    __syncthreads();
    sh[tid] += v;
    __syncthreads();
  }
  u32 base = (tid > 0) ? sh[tid - 1] : 0u;
  for (int i = lo; i < hi; i++) { u32 c = counts[i]; cursor[i] = base; base += c; }
}

// ---- build dst-sorted edge array: tes[pos] = (src, dst, rel, w_bits) ----
__launch_bounds__(256)
__global__ void k_perm(const float* __restrict__ te, u32* __restrict__ cursor,
                       uint4* __restrict__ tes, int E, int N) {
  int tid = blockIdx.x * 256 + threadIdx.x;
  int nth = gridDim.x * 256;
  for (int e = tid; e < E; e += nth) {
    float4 v = *(const float4*)(te + (size_t)e * 4);
    int s = min(max((int)v.x, 0), N - 1);
    int d = min(max((int)v.y, 0), N - 1);
    int r = min(max((int)v.z, 0), 6);
    u32 pos = atomicAdd(&cursor[d], 1u);
    tes[pos] = make_uint4((u32)s, (u32)d, (u32)r, __float_as_uint(v.w));
  }
}

// ---- stage B+C (MFMA, dst-sorted): edge MLP + segmented reduce, few atomics ----
__launch_bounds__(256, 3)
__global__ void k_edge(const uint4* __restrict__ tes, const u16* __restrict__ hb,
                       const float* __restrict__ Wm1, const float* __restrict__ bm1,
                       const float* __restrict__ Wm2, const float* __restrict__ bm2,
                       const float* __restrict__ rel_emb,
                       float* __restrict__ agg, int E, int N, int nranges) {
  __shared__ __align__(16) u16 sWm1[24 * 512];
  __shared__ __align__(16) u16 sWm2[8 * 512];
  __shared__ __align__(16) u16 srel[576];
  __shared__ __align__(16) u16 st[4][16 * 72];

  swizzleW(Wm1, sWm1, 12288, threadIdx.x, 256);
  swizzleW(Wm2, sWm2, 4096, threadIdx.x, 256);
  for (int idx = threadIdx.x; idx < 576; idx += 256) {
    int r = idx / 80, c = idx % 80;
    srel[idx] = (r < 7 && c < 64) ? f2bf(rel_emb[r * 64 + c]) : (u16)0;
  }
  __syncthreads();

  int lane = threadIdx.x & 63, wave = threadIdx.x >> 6;
  int m = lane & 15, quad = lane >> 4, koff = quad * 8, col0 = m;

  float bm1v[4], w192v[4], bm2v[4];
  #pragma unroll
  for (int nt = 0; nt < 4; nt++) {
    int c = nt * 16 + col0;
    bm1v[nt] = bm1[c];
    w192v[nt] = Wm1[192 * 64 + c];
    bm2v[nt] = bm2[c];
  }

  int wid = blockIdx.x * 4 + wave, nw = gridDim.x * 4;
  for (int range = wid; range < nranges; range += nw) {
    int r0 = range * 128;
    int run_dst = -2;       // current run's dst (-2 = none)
    float run = 0.f;        // per-lane partial for column `lane`
    bool bs = false;        // run started at range start?

    #pragma unroll 1
    for (int t8 = 0; t8 < 8; t8++) {
      int p0 = r0 + t8 * 16;
      if (p0 >= E) break;

      int src = 0, dstc = 0, rel = 0, dtag = -1; float w = 0.f;
      if (lane < 16) {
        int p = p0 + lane;
        if (p < E) {
          uint4 v = tes[p];
          src = (int)v.x; dstc = (int)v.y; rel = (int)v.z;
          w = __uint_as_float(v.w);
          dtag = dstc;
        }
      }
      int src_m = __shfl(src, m, 64);
      int dst_m = __shfl(dstc, m, 64);
      int rel_m = __shfl(rel, m, 64);

      const u16* hs = hb + (size_t)src_m * 64;
      const u16* hd = hb + (size_t)dst_m * 64;
      bf16x8 af[6];
      af[0] = *(const bf16x8*)(hs + koff);
      af[1] = *(const bf16x8*)(hs + 32 + koff);
      af[2] = *(const bf16x8*)(hd + koff);
      af[3] = *(const bf16x8*)(hd + 32 + koff);
      af[4] = *(const bf16x8*)(srel + rel_m * 80 + koff);
      af[5] = *(const bf16x8*)(srel + rel_m * 80 + 32 + koff);

      f32x4 acc[4] = {};
      #pragma unroll
      for (int ks = 0; ks < 6; ks++) {
        #pragma unroll
        for (int nt = 0; nt < 4; nt++) {
          bf16x8 b = *(const bf16x8*)(sWm1 + (ks * 4 + nt) * 512 + lane * 8);
          acc[nt] = MFMA(af[ks], b, acc[nt]);
        }
      }

      // epilogue 1: + bm1 + w*Wm1[192], relu, t -> LDS bf16
      float wrow[4];
      #pragma unroll
      for (int r = 0; r < 4; r++) wrow[r] = __shfl(w, quad * 4 + r, 64);
      #pragma unroll
      for (int nt = 0; nt < 4; nt++)
        #pragma unroll
        for (int r = 0; r < 4; r++) {
          float v = fmaf(wrow[r], w192v[nt], acc[nt][r] + bm1v[nt]);
          st[wave][(quad * 4 + r) * 72 + nt * 16 + col0] = f2bf(fmaxf(v, 0.f));
        }
      __builtin_amdgcn_wave_barrier();

      f32x4 acc2[4] = {};
      #pragma unroll
      for (int ks = 0; ks < 2; ks++) {
        bf16x8 a2 = *(const bf16x8*)(st[wave] + m * 72 + ks * 32 + koff);
        #pragma unroll
        for (int nt = 0; nt < 4; nt++) {
          bf16x8 b = *(const bf16x8*)(sWm2 + (ks * 4 + nt) * 512 + lane * 8);
          acc2[nt] = MFMA(a2, b, acc2[nt]);
        }
      }
      __builtin_amdgcn_wave_barrier();

      // message rows (+bm2) back to st (bf16), row-major
      #pragma unroll
      for (int nt = 0; nt < 4; nt++)
        #pragma unroll
        for (int r = 0; r < 4; r++)
          st[wave][(quad * 4 + r) * 72 + nt * 16 + col0] =
              f2bf(acc2[nt][r] + bm2v[nt]);
      __builtin_amdgcn_wave_barrier();

      // segmented reduce over the 16 rows; column = lane
      #pragma unroll 1
      for (int r = 0; r < 16; r++) {
        int d = __shfl(dtag, r, 64);                 // uniform broadcast
        float val = bf2f(st[wave][r * 72 + lane]);
        if (d != run_dst) {
          if (run_dst >= 0) {
            float* ap = agg + (size_t)run_dst * 64 + lane;
            if (bs) atomicAdd(ap, run); else *ap = run;
          }
          run_dst = d; run = val; bs = (t8 == 0 && r == 0);
        } else {
          run += val;
        }
      }
      __builtin_amdgcn_wave_barrier();
    }
    if (run_dst >= 0) atomicAdd(agg + (size_t)run_dst * 64 + lane, run);
  }
}

// ---- stage D: nodes = LN(h+agg); column sum+max; last block runs final MLP ----
__launch_bounds__(256)
__global__ void k_nodes(const u16* __restrict__ hb, const float* __restrict__ agg,
                        const float* __restrict__ gn, const float* __restrict__ bn,
                        const float* __restrict__ Wg1, const float* __restrict__ bg1,
                        const float* __restrict__ Wg2, const float* __restrict__ bg2,
                        float* __restrict__ gsum, u32* __restrict__ gmax,
                        u32* __restrict__ done, float* __restrict__ out, int N) {
  int lane = threadIdx.x & 63, wave = threadIdx.x >> 6;
  int wid = blockIdx.x * 4 + wave;
  int nw = gridDim.x * 4;
  float gnv = gn[lane], bnv = bn[lane];
  float sj = 0.f, mj = -3.0e38f;
  for (int n = wid; n < N; n += nw) {
    float v = bf2f(hb[(size_t)n * 64 + lane]) + agg[(size_t)n * 64 + lane];
    float s = v;
    #pragma unroll
    for (int m = 32; m >= 1; m >>= 1) s += __shfl_xor(s, m, 64);
    float mu = s * (1.f / 64.f);
    float d = v - mu;
    float q = d * d;
    #pragma unroll
    for (int m = 32; m >= 1; m >>= 1) q += __shfl_xor(q, m, 64);
    float rs = rsqrtf(q * (1.f / 64.f) + EPS);
    float val = fmaf(d * rs, gnv, bnv);
    sj += val;
    mj = fmaxf(mj, val);
  }
  __shared__ float bs[256], bm[256];
  bs[threadIdx.x] = sj;
  bm[threadIdx.x] = mj;
  __syncthreads();
  if (threadIdx.x < 64) {
    int t = threadIdx.x;
    float ts = bs[t] + bs[64 + t] + bs[128 + t] + bs[192 + t];
    float tm = fmaxf(fmaxf(bm[t], bm[64 + t]), fmaxf(bm[128 + t], bm[192 + t]));
    atomicAdd(gsum + t, ts);
    atomicMax(gmax + t, fkey(tm));
  }

  // last block performs the final tiny MLP
  __threadfence();
  __shared__ u32 lastv;
  if (threadIdx.x == 0) lastv = atomicAdd(done, 1u);
  __syncthreads();
  if (lastv == gridDim.x - 1) {
    __shared__ float g[128];
    __shared__ float y1[64];
    int t = threadIdx.x;
    if (t < 64) {
      float sv = __hip_atomic_load(&gsum[t], __ATOMIC_RELAXED, __HIP_MEMORY_SCOPE_AGENT);
      g[t] = sv / (float)N;
    } else if (t < 128) {
      u32 k = __hip_atomic_load(&gmax[t - 64], __ATOMIC_RELAXED, __HIP_MEMORY_SCOPE_AGENT);
      u32 b = (k & 0x80000000u) ? (k & 0x7fffffffu) : ~k;
      g[t] = __uint_as_float(b);
    }
    __syncthreads();
    if (t < 64) {
      float a = bg1[t];
      for (int i = 0; i < 128; i++) a = fmaf(g[i], Wg1[i * 64 + t], a);
      y1[t] = fmaxf(a, 0.f);
    }
    __syncthreads();
    if (t < 64) {
      float a = bg2[t];
      for (int k = 0; k < 64; k++) a = fmaf(y1[k], Wg2[k * 64 + t], a);
      out[t] = a;
    }
  }
}

extern "C" void kernel_launch(void* const* d_in, const int* in_sizes, int n_in,
                              void* d_out, int out_size, void* d_ws, size_t ws_size,
                              hipStream_t stream) {
  const int N = in_sizes[0] / 256;
  const int E = in_sizes[1] / 4;
  const int Mp = (N + 63) & ~63;

  float* agg    = (float*)d_ws;                        // N*64 f32
  float* gsum   = agg + (size_t)N * 64;                // 64 f32
  u32*   gmax   = (u32*)(gsum + 64);                   // 64 u32
  u32*   done   = gmax + 64;                           // 64 u32 (1 used)
  u32*   counts = done + 64;                           // Mp u32
  u32*   cursor = counts + Mp;                         // Mp u32
  uint4* tes    = (uint4*)(cursor + Mp);               // E uint4 (16B-aligned)
  u16*   hb     = (u16*)(tes + E);                     // N*64 bf16
  size_t zeroB  = ((size_t)N * 64 + 192 + Mp) * 4;     // agg..counts

  const float* X  = (const float*)d_in[0];
  const float* te = (const float*)d_in[1];

  hipMemsetAsync(agg, 0, zeroB, stream);
  hipLaunchKernelGGL(k_h, dim3(800), dim3(256), 0, stream, X,
                     (const float*)d_in[2], (const float*)d_in[3], (const float*)d_in[4],
                     (const float*)d_in[5], (const float*)d_in[6], (const float*)d_in[7],
                     te, counts, hb, N, E);
  hipLaunchKernelGGL(k_scan, dim3(1), dim3(1024), 0, stream, counts, cursor, N);
  hipLaunchKernelGGL(k_perm, dim3(800), dim3(256), 0, stream, te, cursor, tes, E, N);
  int nranges = (E + 127) / 128;
  hipLaunchKernelGGL(k_edge, dim3(768), dim3(256), 0, stream, tes, hb,
                     (const float*)d_in[9], (const float*)d_in[10],
                     (const float*)d_in[11], (const float*)d_in[12],
                     (const float*)d_in[8], agg, E, N, nranges);
  hipLaunchKernelGGL(k_nodes, dim3(2048), dim3(256), 0, stream, hb, agg,
                     (const float*)d_in[13], (const float*)d_in[14],
                     (const float*)d_in[15], (const float*)d_in[16],
                     (const float*)d_in[17], (const float*)d_in[18],
                     gsum, gmax, done, (float*)d_out, N);
}